// Round 1
// 155.932 us; speedup vs baseline: 1.1693x; 1.1693x over previous
//
#include <hip/hip_runtime.h>
#include <hip/hip_bf16.h>
#include <math.h>

#define NN 20000
#define NE 320000
#define BN_EPS 1e-5f
#define CAP 64            // per-node edge-bucket capacity (max in-degree ~40 for this data)

// ---- workspace layout ----
#define MSG_BYTES   (NE * 16 * 4)            // 20,480,000  per-edge messages (non-atomic)
#define ELIST_OFF   MSG_BYTES
#define ELIST_BYTES (NN * CAP * 4)           //  5,120,000  bucketed edge ids
#define CNT_OFF     (ELIST_OFF + ELIST_BYTES)
#define CNT_BYTES   (NN * 4)                 //     80,000  in-degree counters
#define BNACC_OFF   (CNT_OFF + CNT_BYTES)    // 128 B BN accumulators
#define EXTRA_OFF   (BNACC_OFF + 128)
#define EXTRA_BYTES (NN * 16 * 4)            //  1,280,000  overflow fallback (atomic)
#define Y_OFF       (EXTRA_OFF + EXTRA_BYTES)
// memset region: cnt + bnacc + extra (contiguous)
#define ZERO_OFF    CNT_OFF
#define ZERO_BYTES  (CNT_BYTES + 128 + EXTRA_BYTES)

typedef __bf16 bf16x8 __attribute__((ext_vector_type(8)));
typedef float  f32x4  __attribute__((ext_vector_type(4)));

union BF8 { bf16x8 v; unsigned short us[8]; unsigned int ui[4]; };

__device__ __forceinline__ unsigned short f2bf(float f) {
    unsigned int u = __builtin_bit_cast(unsigned int, f);
    u += 0x7FFFu + ((u >> 16) & 1u);   // RNE
    return (unsigned short)(u >> 16);
}
__device__ __forceinline__ float bf2f(unsigned short s) {
    unsigned int u = ((unsigned int)s) << 16;
    return __builtin_bit_cast(float, u);
}
__device__ __forceinline__ unsigned int pack2bf(float a, float b) {
    return (unsigned int)f2bf(a) | ((unsigned int)f2bf(b) << 16);
}

// ============================ edge path (+fused self stats) ============================
// Compute path identical to the verified 183us kernel. Output path changed:
//   - per edge: ONE returning atomicAdd on cnt[dst] (q==0 lanes), edge id into elist bucket
//   - msg written coalesced (float4) to msg[e][16] -- NO per-component atomics
//   - bucket overflow (deg>CAP, ~never for this data): fp32 atomics into `extra`
// This cuts device-scope fabric atomics 16x (5.12M -> 0.32M); the old kernel was pinned
// at ~53 Gatomic/s (WRITE_SIZE 81MB == 5.12M x 16B RMW granules at the coherence point).
__global__ __launch_bounds__(256, 4) void edge_kernel(
    const float* __restrict__ h_neigh, const float* __restrict__ efeat,
    const int* __restrict__ src, const int* __restrict__ dst,
    const float* __restrict__ We1, const float* __restrict__ be1,
    const float* __restrict__ We2, const float* __restrict__ be2,
    float* __restrict__ msgb, int* __restrict__ elist,
    int* __restrict__ cnt, float* __restrict__ extra,
    const float* __restrict__ h_self, const float* __restrict__ Wsf,
    float* __restrict__ y, float* __restrict__ bnacc)
{
    // A-frag-swizzled We2^T: [mb][kb][lane][j]  32 KB
    __shared__ __align__(16) unsigned short A3sw[16 * 2 * 64 * 8];
    __shared__ float red[4][32];   // self-path block reduction

    const int t = threadIdx.x;

    // ---- init A3sw from We2 (coalesced float4 reads, swizzled b16 writes)
    {
        const float4* W2v = (const float4*)We2;
#pragma unroll
        for (int it = 0; it < 16; it++) {
            int c4 = t + 256 * it;          // 0..4095 float4 chunks
            float4 w = W2v[c4];
            int f = c4 * 4;
            int h = f >> 8, c = f & 255;
            int mb = c >> 4, kb = h >> 5, hh = h & 31, co = c & 15;
            int base = ((mb * 2 + kb) * 64 + (hh >> 3) * 16) * 8 + (hh & 7);
            A3sw[base + (co + 0) * 8] = f2bf(w.x);
            A3sw[base + (co + 1) * 8] = f2bf(w.y);
            A3sw[base + (co + 2) * 8] = f2bf(w.z);
            A3sw[base + (co + 3) * 8] = f2bf(w.w);
        }
    }
    __syncthreads();

    const int L = t & 63, wv = t >> 6;
    const int lo16 = L & 15, q = L >> 4;
    const int qc = q & 1;
    const bool qlow = (q < 2);
    const bool qhi1 = ((q >> 1) != 0);   // target-side chunk select

    // ---- We1^T A-frags (hi/lo) in registers, bias in slot k=16
    BF8 w1h[4], w1l[4];
#pragma unroll
    for (int c = 0; c < 4; c++) {
#pragma unroll
        for (int j = 0; j < 8; j++) {
            float w;
            if (q < 2)                 w = We1[(q * 8 + j) * 64 + c * 16 + lo16];
            else if (q == 2 && j == 0) w = be1[c * 16 + lo16];
            else                       w = 0.f;
            unsigned short h = f2bf(w);
            w1h[c].us[j] = h;
            w1l[c].us[j] = f2bf(w - bf2f(h));
        }
    }

    // A-frag of be2^T
    BF8 be2T;
#pragma unroll
    for (int j = 0; j < 8; j++) {
        float bv = be2[(qc * 8 + j) * 16 + lo16];
        be2T.us[j] = qlow ? f2bf(bv) : (unsigned short)0;
    }

    // bpermute source-lane byte addresses (loop-invariant)
    const int addrA = (((q & 1) * 2 + 0) * 16 + lo16) * 4;
    const int addrB = (((q & 1) * 2 + 1) * 16 + lo16) * 4;

    for (int bt = blockIdx.x; bt < NE / 64; bt += gridDim.x) {
        int e = bt * 64 + wv * 16 + lo16;
        int se = src[e];
        int de = dst[e];

        // ---- bucket build: one returning atomic per edge (q==0 lanes own edges).
        // Issued early; latency hides under stage2/3 compute. kk broadcast at the end.
        int kv = 0;
        if (q == 0) {
            kv = atomicAdd(&cnt[de], 1);
            if (kv < CAP) elist[de * CAP + kv] = e;
        }

        float xr[16];
        {
            const float4* xp = (const float4*)(h_neigh + (size_t)se * 16);
#pragma unroll
            for (int k4 = 0; k4 < 4; k4++) {
                float4 a = xp[k4];
                xr[k4*4+0] = a.x; xr[k4*4+1] = a.y; xr[k4*4+2] = a.z; xr[k4*4+3] = a.w;
            }
        }

        // B-frag of ef^T (hi/lo), bias partner 1.0 at (q==2, j==0)
        BF8 a2h, a2l;
        {
            const float4* ep = (const float4*)(efeat + (size_t)e * 16 + qc * 8);
            float4 e0 = ep[0], e1 = ep[1];
            float ev[8] = {e0.x, e0.y, e0.z, e0.w, e1.x, e1.y, e1.z, e1.w};
#pragma unroll
            for (int j = 0; j < 8; j++) {
                if (qlow) {
                    unsigned short h = f2bf(ev[j]);
                    a2h.us[j] = h;
                    a2l.us[j] = f2bf(ev[j] - bf2f(h));
                } else {
                    a2h.us[j] = (q == 2 && j == 0) ? (unsigned short)0x3F80 : (unsigned short)0;
                    a2l.us[j] = 0;
                }
            }
        }

        // stage 2T: ehT chunk c holds rows h = c*16 + q*4 + r, col = edge lo16
        float vch[4][4];
#pragma unroll
        for (int c = 0; c < 4; c++) {
            f32x4 c2 = {0.f, 0.f, 0.f, 0.f};
            c2 = __builtin_amdgcn_mfma_f32_16x16x32_bf16(w1h[c].v, a2h.v, c2, 0, 0, 0);
            c2 = __builtin_amdgcn_mfma_f32_16x16x32_bf16(w1l[c].v, a2h.v, c2, 0, 0, 0);
            c2 = __builtin_amdgcn_mfma_f32_16x16x32_bf16(w1h[c].v, a2l.v, c2, 0, 0, 0);
#pragma unroll
            for (int r = 0; r < 4; r++) vch[c][r] = fmaxf(c2[r], 0.f);
        }

        // pack hi/lo dword pairs
        unsigned int dwH[4][2], dwL[4][2];
#pragma unroll
        for (int c = 0; c < 4; c++) {
#pragma unroll
            for (int d = 0; d < 2; d++) {
                float va = vch[c][2*d], vb = vch[c][2*d+1];
                unsigned short ha = f2bf(va), hb = f2bf(vb);
                dwH[c][d] = (unsigned int)ha | ((unsigned int)hb << 16);
                dwL[c][d] = pack2bf(va - bf2f(ha), vb - bf2f(hb));
            }
        }

        // pulls -> stage-3 B-frags: pull BOTH chunk candidates, select by q>>1
        BF8 b3h[2], b3l[2];
#pragma unroll
        for (int kb = 0; kb < 2; kb++) {
#pragma unroll
            for (int tt = 0; tt < 4; tt++) {
                int d = tt & 1;
                int addr = (tt >> 1) ? addrB : addrA;
                int h0 = __builtin_amdgcn_ds_bpermute(addr, (int)dwH[kb*2+0][d]);
                int h1 = __builtin_amdgcn_ds_bpermute(addr, (int)dwH[kb*2+1][d]);
                int l0 = __builtin_amdgcn_ds_bpermute(addr, (int)dwL[kb*2+0][d]);
                int l1 = __builtin_amdgcn_ds_bpermute(addr, (int)dwL[kb*2+1][d]);
                b3h[kb].ui[tt] = (unsigned int)(qhi1 ? h1 : h0);
                b3l[kb].ui[tt] = (unsigned int)(qhi1 ? l1 : l0);
            }
        }

        // be2 term: msg = be2^T @ x^T
        BF8 xT;
#pragma unroll
        for (int j = 0; j < 8; j++)
            xT.us[j] = qlow ? f2bf(xr[qc * 8 + j]) : (unsigned short)0;
        f32x4 msg = {0.f, 0.f, 0.f, 0.f};
        msg = __builtin_amdgcn_mfma_f32_16x16x32_bf16(be2T.v, xT.v, msg, 0, 0, 0);

        // stage 3: per mb(=i): C = We2^T @ ehT, msg += x[i]*C
#pragma unroll 4
        for (int mb = 0; mb < 16; mb++) {
            bf16x8 a3a = *(const bf16x8*)&A3sw[((mb * 2 + 0) * 64 + L) * 8];
            bf16x8 a3b = *(const bf16x8*)&A3sw[((mb * 2 + 1) * 64 + L) * 8];
            f32x4 acc = {0.f, 0.f, 0.f, 0.f};
            acc = __builtin_amdgcn_mfma_f32_16x16x32_bf16(a3a, b3h[0].v, acc, 0, 0, 0);
            acc = __builtin_amdgcn_mfma_f32_16x16x32_bf16(a3b, b3h[1].v, acc, 0, 0, 0);
            acc = __builtin_amdgcn_mfma_f32_16x16x32_bf16(a3a, b3l[0].v, acc, 0, 0, 0);
            acc = __builtin_amdgcn_mfma_f32_16x16x32_bf16(a3b, b3l[1].v, acc, 0, 0, 0);
            float xm = xr[mb];
            msg[0] += xm * acc[0];
            msg[1] += xm * acc[1];
            msg[2] += xm * acc[2];
            msg[3] += xm * acc[3];
        }

        // ---- emit: coalesced msg store (64 lanes cover contiguous 4KB) or overflow atomics
        int kk = __shfl(kv, lo16);      // broadcast bucket slot from the q==0 owner lane
        if (kk < CAP) {
            *(float4*)(msgb + (size_t)e * 16 + q * 4) =
                make_float4(msg[0], msg[1], msg[2], msg[3]);
        } else {
            float* xp = extra + (size_t)de * 16 + q * 4;
#pragma unroll
            for (int r = 0; r < 4; r++) atomicAdd(xp + r, msg[r]);
        }
    }

    // ---------------- fused self path (blocks 945..1023) ----------------
    int sb = (int)blockIdx.x - 945;
    if (sb >= 0 && sb < 79) {
        int n = sb * 256 + t;
        bool act = (n < NN);
        float hv[16], yv[16];
        if (act) {
            const float4* h4 = (const float4*)(h_self + (size_t)n * 16);
#pragma unroll
            for (int k = 0; k < 4; k++) {
                float4 a = h4[k];
                hv[4*k+0] = a.x; hv[4*k+1] = a.y; hv[4*k+2] = a.z; hv[4*k+3] = a.w;
            }
        } else {
#pragma unroll
            for (int i = 0; i < 16; i++) hv[i] = 0.f;
        }
#pragma unroll
        for (int o = 0; o < 16; o++) {
            float a = 0.f;
#pragma unroll
            for (int i = 0; i < 16; i++) a += hv[i] * Wsf[i*16 + o];
            yv[o] = a;
        }
        if (act) {
            float4* y4 = (float4*)(y + (size_t)n * 16);
#pragma unroll
            for (int k = 0; k < 4; k++)
                y4[k] = make_float4(yv[4*k+0], yv[4*k+1], yv[4*k+2], yv[4*k+3]);
        }
        int lane = t & 63;
#pragma unroll
        for (int o = 0; o < 16; o++) {
            float a = act ? yv[o] : 0.f;
            float b = act ? yv[o]*yv[o] : 0.f;
#pragma unroll
            for (int off = 32; off > 0; off >>= 1) {
                a += __shfl_down(a, off);
                b += __shfl_down(b, off);
            }
            if (lane == 0) { red[wv][o] = a; red[wv][16 + o] = b; }
        }
        __syncthreads();
        if (t < 32) {
            float s = red[0][t] + red[1][t] + red[2][t] + red[3][t];
            atomicAdd(&bnacc[t], s);
        }
    }
}

// ---- finalize: per-node msg gather-sum + BN + tanh + add + relu + L2-normalize ----
// 4 threads per node; thread c owns components c*4..c*4+3. Per edge the node's 4
// adjacent lanes read a contiguous 64B msg row (coalesced).
__global__ __launch_bounds__(256) void final_kernel(
    const float* __restrict__ msgb, const int* __restrict__ elist,
    const int* __restrict__ cnt, const float* __restrict__ extra,
    const float* __restrict__ y, const float* __restrict__ bnacc,
    const float* __restrict__ gamma, const float* __restrict__ beta,
    float* __restrict__ out)
{
    int tb = blockIdx.x * 256 + threadIdx.x;
    int n = tb >> 2, c = tb & 3;
    if (n >= NN) return;

    int deg = cnt[n];
    int m = deg < CAP ? deg : CAP;
    const float4* m4 = (const float4*)msgb;
    const int* el = elist + n * CAP;

    float ax = 0.f, ay = 0.f, az = 0.f, aw = 0.f;
    int k = 0;
    for (; k + 4 <= m; k += 4) {
        int e0 = el[k], e1 = el[k+1], e2 = el[k+2], e3 = el[k+3];
        float4 a0 = m4[(size_t)e0*4 + c];
        float4 a1 = m4[(size_t)e1*4 + c];
        float4 a2 = m4[(size_t)e2*4 + c];
        float4 a3 = m4[(size_t)e3*4 + c];
        ax += (a0.x + a1.x) + (a2.x + a3.x);
        ay += (a0.y + a1.y) + (a2.y + a3.y);
        az += (a0.z + a1.z) + (a2.z + a3.z);
        aw += (a0.w + a1.w) + (a2.w + a3.w);
    }
    for (; k < m; k++) {
        int e0 = el[k];
        float4 a0 = m4[(size_t)e0*4 + c];
        ax += a0.x; ay += a0.y; az += a0.z; aw += a0.w;
    }
    if (deg > CAP) {
        float4 a0 = *(const float4*)(extra + (size_t)n * 16 + c * 4);
        ax += a0.x; ay += a0.y; az += a0.z; aw += a0.w;
    }

    float4 yv4 = ((const float4*)y)[(size_t)n * 4 + c];
    float yv[4] = {yv4.x, yv4.y, yv4.z, yv4.w};
    float nb[4] = {ax, ay, az, aw};

    const float inv_n = 1.f / (float)NN;
    float z[4];
    float ss = 0.f;
#pragma unroll
    for (int r = 0; r < 4; r++) {
        int o = c * 4 + r;
        float mu  = bnacc[o] * inv_n;
        float var = bnacc[16 + o] * inv_n - mu * mu;
        float inv = rsqrtf(var + BN_EPS);
        float yy  = (yv[r] - mu) * inv * gamma[o] + beta[o];
        float tt  = tanhf(yy);
        float zz  = fmaxf(tt + nb[r], 0.f);
        z[r] = zz;
        ss += zz * zz;
    }
    // node-wide sum of squares across the 4 owning lanes (quad never crosses a wave)
    ss += __shfl_xor(ss, 1);
    ss += __shfl_xor(ss, 2);
    float nrm = sqrtf(ss);
    if (nrm == 0.f) nrm = 1.f;
    float rr = 1.f / nrm;
    *(float4*)(out + (size_t)n * 16 + c * 4) =
        make_float4(z[0]*rr, z[1]*rr, z[2]*rr, z[3]*rr);
}

extern "C" void kernel_launch(void* const* d_in, const int* in_sizes, int n_in,
                              void* d_out, int out_size, void* d_ws, size_t ws_size,
                              hipStream_t stream) {
    const float* h_neigh = (const float*)d_in[0];
    const float* h_self  = (const float*)d_in[1];
    const float* efeat   = (const float*)d_in[2];
    const int*   src     = (const int*)d_in[3];
    const int*   dst     = (const int*)d_in[4];
    const float* W_self  = (const float*)d_in[5];
    const float* gamma   = (const float*)d_in[6];
    const float* beta    = (const float*)d_in[7];
    const float* We1     = (const float*)d_in[8];
    const float* be1     = (const float*)d_in[9];
    const float* We2     = (const float*)d_in[10];
    const float* be2     = (const float*)d_in[11];
    float* out = (float*)d_out;

    char* ws = (char*)d_ws;
    float* msgb  = (float*)ws;
    int*   elist = (int*)(ws + ELIST_OFF);
    int*   cnt   = (int*)(ws + CNT_OFF);
    float* bnacc = (float*)(ws + BNACC_OFF);
    float* extra = (float*)(ws + EXTRA_OFF);
    float* y     = (float*)(ws + Y_OFF);

    // zero cnt + BN accumulators + overflow buffer (ws poisoned 0xAA each call)
    hipMemsetAsync(ws + ZERO_OFF, 0, ZERO_BYTES, stream);

    // 1024 blocks = 4/CU resident; grid-stride over 5000 wave-tile groups;
    // blocks 945..1023 also do the self path.
    edge_kernel<<<1024, 256, 0, stream>>>(
        h_neigh, efeat, src, dst, We1, be1, We2, be2,
        msgb, elist, cnt, extra,
        h_self, W_self, y, bnacc);
    final_kernel<<<(NN * 4 + 255) / 256, 256, 0, stream>>>(
        msgb, elist, cnt, extra, y, bnacc, gamma, beta, out);
}

// Round 3
// 155.608 us; speedup vs baseline: 1.1717x; 1.0021x over previous
//
#include <hip/hip_runtime.h>
#include <hip/hip_bf16.h>
#include <math.h>

#define NN 20000
#define NE 320000
#define BN_EPS 1e-5f
#define CAP 48            // per-node edge-bucket capacity (max in-degree ~40 for this data)
#define CNTP 16           // cnt padding: one counter per 64B (2/128B-line; kills RMW queueing)

// ---- workspace layout (total 28,160,128 B -- below the 28,240,128 that passed in R1) ----
#define MSG_BYTES   (NE * 16 * 4)            // 20,480,000  per-edge messages (non-atomic)
#define ELIST_OFF   MSG_BYTES
#define ELIST_BYTES (NN * CAP * 4)           //  3,840,000  bucketed edge ids
#define CNT_OFF     (ELIST_OFF + ELIST_BYTES)
#define CNT_BYTES   (NN * CNTP * 4)          //  1,280,000  padded in-degree counters
#define BNACC_OFF   (CNT_OFF + CNT_BYTES)    // 128 B BN accumulators
#define EXTRA_OFF   (BNACC_OFF + 128)
#define EXTRA_BYTES (NN * 16 * 4)            //  1,280,000  overflow fallback (atomic)
#define Y_OFF       (EXTRA_OFF + EXTRA_BYTES)
// memset region: cntp + bnacc + extra (contiguous)
#define ZERO_OFF    CNT_OFF
#define ZERO_BYTES  (CNT_BYTES + 128 + EXTRA_BYTES)

typedef __bf16 bf16x8 __attribute__((ext_vector_type(8)));
typedef float  f32x4  __attribute__((ext_vector_type(4)));

union BF8 { bf16x8 v; unsigned short us[8]; unsigned int ui[4]; };

__device__ __forceinline__ unsigned short f2bf(float f) {
    unsigned int u = __builtin_bit_cast(unsigned int, f);
    u += 0x7FFFu + ((u >> 16) & 1u);   // RNE
    return (unsigned short)(u >> 16);
}
__device__ __forceinline__ float bf2f(unsigned short s) {
    unsigned int u = ((unsigned int)s) << 16;
    return __builtin_bit_cast(float, u);
}
__device__ __forceinline__ unsigned int pack2bf(float a, float b) {
    return (unsigned int)f2bf(a) | ((unsigned int)f2bf(b) << 16);
}

// ============================ edge path (+fused self stats) ============================
// Compute path identical to the verified kernel. R3 = R2's atomic-latency attack with the
// risk stripped out (R2 container failure suspected ws overflow from CNTP=32 padding):
//   - cnt padded to 1 counter / 64B (per-128B-line RMW depth 512 -> ~32, spread over kernel)
//   - next tile's {src,dst loads + counter atomic} fired at loop top (full iter of slack
//     for the contended return; dependent gather loads issue ahead of this iter's stores
//     in the in-order vmcnt FIFO)
//   - msgb store unconditional; elist write deferred to iteration end
//   - grid/LDS/occupancy identical to the R1-passing config (1024 blocks, 4/CU, 33280B LDS)
__global__ __launch_bounds__(256, 4) void edge_kernel(
    const float* __restrict__ h_neigh, const float* __restrict__ efeat,
    const int* __restrict__ src, const int* __restrict__ dst,
    const float* __restrict__ We1, const float* __restrict__ be1,
    const float* __restrict__ We2, const float* __restrict__ be2,
    float* __restrict__ msgb, int* __restrict__ elist,
    int* __restrict__ cntp, float* __restrict__ extra,
    const float* __restrict__ h_self, const float* __restrict__ Wsf,
    float* __restrict__ y, float* __restrict__ bnacc)
{
    // A-frag-swizzled We2^T: [mb][kb][lane][j]  32 KB
    __shared__ __align__(16) unsigned short A3sw[16 * 2 * 64 * 8];
    __shared__ float red[4][32];   // self-path block reduction

    const int t = threadIdx.x;

    // ---- init A3sw from We2 (coalesced float4 reads, swizzled b16 writes)
    {
        const float4* W2v = (const float4*)We2;
#pragma unroll
        for (int it = 0; it < 16; it++) {
            int c4 = t + 256 * it;          // 0..4095 float4 chunks
            float4 w = W2v[c4];
            int f = c4 * 4;
            int h = f >> 8, c = f & 255;
            int mb = c >> 4, kb = h >> 5, hh = h & 31, co = c & 15;
            int base = ((mb * 2 + kb) * 64 + (hh >> 3) * 16) * 8 + (hh & 7);
            A3sw[base + (co + 0) * 8] = f2bf(w.x);
            A3sw[base + (co + 1) * 8] = f2bf(w.y);
            A3sw[base + (co + 2) * 8] = f2bf(w.z);
            A3sw[base + (co + 3) * 8] = f2bf(w.w);
        }
    }
    __syncthreads();

    const int L = t & 63, wv = t >> 6;
    const int lo16 = L & 15, q = L >> 4;
    const int qc = q & 1;
    const bool qlow = (q < 2);
    const bool qhi1 = ((q >> 1) != 0);   // target-side chunk select

    // ---- We1^T A-frags (hi/lo) in registers, bias in slot k=16
    BF8 w1h[4], w1l[4];
#pragma unroll
    for (int c = 0; c < 4; c++) {
#pragma unroll
        for (int j = 0; j < 8; j++) {
            float w;
            if (q < 2)                 w = We1[(q * 8 + j) * 64 + c * 16 + lo16];
            else if (q == 2 && j == 0) w = be1[c * 16 + lo16];
            else                       w = 0.f;
            unsigned short h = f2bf(w);
            w1h[c].us[j] = h;
            w1l[c].us[j] = f2bf(w - bf2f(h));
        }
    }

    // A-frag of be2^T
    BF8 be2T;
#pragma unroll
    for (int j = 0; j < 8; j++) {
        float bv = be2[(qc * 8 + j) * 16 + lo16];
        be2T.us[j] = qlow ? f2bf(bv) : (unsigned short)0;
    }

    // bpermute source-lane byte addresses (loop-invariant)
    const int addrA = (((q & 1) * 2 + 0) * 16 + lo16) * 4;
    const int addrB = (((q & 1) * 2 + 1) * 16 + lo16) * 4;

    const int NT = NE / 64;
    int bt = blockIdx.x;
    {
        // ---- pipeline prologue: tile 0 loads + counter atomic
        int e = bt * 64 + wv * 16 + lo16;
        int se = src[e];
        int de = dst[e];
        int kv = 0;
        if (q == 0) kv = atomicAdd(&cntp[de * CNTP], 1);

        while (true) {
            // ---- fire NEXT tile's loads + atomic (return hides under this iter's compute)
            int btn = bt + gridDim.x;
            bool hn = btn < NT;
            int en = 0, sen = 0, den = 0, kvn = 0;
            if (hn) {
                en = btn * 64 + wv * 16 + lo16;
                sen = src[en];
                den = dst[en];
                if (q == 0) kvn = atomicAdd(&cntp[den * CNTP], 1);
            }

            float xr[16];
            {
                const float4* xp = (const float4*)(h_neigh + (size_t)se * 16);
#pragma unroll
                for (int k4 = 0; k4 < 4; k4++) {
                    float4 a = xp[k4];
                    xr[k4*4+0] = a.x; xr[k4*4+1] = a.y; xr[k4*4+2] = a.z; xr[k4*4+3] = a.w;
                }
            }

            // B-frag of ef^T (hi/lo), bias partner 1.0 at (q==2, j==0)
            BF8 a2h, a2l;
            {
                const float4* ep = (const float4*)(efeat + (size_t)e * 16 + qc * 8);
                float4 e0 = ep[0], e1 = ep[1];
                float ev[8] = {e0.x, e0.y, e0.z, e0.w, e1.x, e1.y, e1.z, e1.w};
#pragma unroll
                for (int j = 0; j < 8; j++) {
                    if (qlow) {
                        unsigned short h = f2bf(ev[j]);
                        a2h.us[j] = h;
                        a2l.us[j] = f2bf(ev[j] - bf2f(h));
                    } else {
                        a2h.us[j] = (q == 2 && j == 0) ? (unsigned short)0x3F80 : (unsigned short)0;
                        a2l.us[j] = 0;
                    }
                }
            }

            // stage 2T: ehT chunk c holds rows h = c*16 + q*4 + r, col = edge lo16
            float vch[4][4];
#pragma unroll
            for (int c = 0; c < 4; c++) {
                f32x4 c2 = {0.f, 0.f, 0.f, 0.f};
                c2 = __builtin_amdgcn_mfma_f32_16x16x32_bf16(w1h[c].v, a2h.v, c2, 0, 0, 0);
                c2 = __builtin_amdgcn_mfma_f32_16x16x32_bf16(w1l[c].v, a2h.v, c2, 0, 0, 0);
                c2 = __builtin_amdgcn_mfma_f32_16x16x32_bf16(w1h[c].v, a2l.v, c2, 0, 0, 0);
#pragma unroll
                for (int r = 0; r < 4; r++) vch[c][r] = fmaxf(c2[r], 0.f);
            }

            // pack hi/lo dword pairs
            unsigned int dwH[4][2], dwL[4][2];
#pragma unroll
            for (int c = 0; c < 4; c++) {
#pragma unroll
                for (int d = 0; d < 2; d++) {
                    float va = vch[c][2*d], vb = vch[c][2*d+1];
                    unsigned short ha = f2bf(va), hb = f2bf(vb);
                    dwH[c][d] = (unsigned int)ha | ((unsigned int)hb << 16);
                    dwL[c][d] = pack2bf(va - bf2f(ha), vb - bf2f(hb));
                }
            }

            // pulls -> stage-3 B-frags: pull BOTH chunk candidates, select by q>>1
            BF8 b3h[2], b3l[2];
#pragma unroll
            for (int kb = 0; kb < 2; kb++) {
#pragma unroll
                for (int tt = 0; tt < 4; tt++) {
                    int d = tt & 1;
                    int addr = (tt >> 1) ? addrB : addrA;
                    int h0 = __builtin_amdgcn_ds_bpermute(addr, (int)dwH[kb*2+0][d]);
                    int h1 = __builtin_amdgcn_ds_bpermute(addr, (int)dwH[kb*2+1][d]);
                    int l0 = __builtin_amdgcn_ds_bpermute(addr, (int)dwL[kb*2+0][d]);
                    int l1 = __builtin_amdgcn_ds_bpermute(addr, (int)dwL[kb*2+1][d]);
                    b3h[kb].ui[tt] = (unsigned int)(qhi1 ? h1 : h0);
                    b3l[kb].ui[tt] = (unsigned int)(qhi1 ? l1 : l0);
                }
            }

            // be2 term: msg = be2^T @ x^T
            BF8 xT;
#pragma unroll
            for (int j = 0; j < 8; j++)
                xT.us[j] = qlow ? f2bf(xr[qc * 8 + j]) : (unsigned short)0;
            f32x4 msg = {0.f, 0.f, 0.f, 0.f};
            msg = __builtin_amdgcn_mfma_f32_16x16x32_bf16(be2T.v, xT.v, msg, 0, 0, 0);

            // stage 3: per mb(=i): C = We2^T @ ehT, msg += x[i]*C
#pragma unroll 4
            for (int mb = 0; mb < 16; mb++) {
                bf16x8 a3a = *(const bf16x8*)&A3sw[((mb * 2 + 0) * 64 + L) * 8];
                bf16x8 a3b = *(const bf16x8*)&A3sw[((mb * 2 + 1) * 64 + L) * 8];
                f32x4 acc = {0.f, 0.f, 0.f, 0.f};
                acc = __builtin_amdgcn_mfma_f32_16x16x32_bf16(a3a, b3h[0].v, acc, 0, 0, 0);
                acc = __builtin_amdgcn_mfma_f32_16x16x32_bf16(a3b, b3h[1].v, acc, 0, 0, 0);
                acc = __builtin_amdgcn_mfma_f32_16x16x32_bf16(a3a, b3l[0].v, acc, 0, 0, 0);
                acc = __builtin_amdgcn_mfma_f32_16x16x32_bf16(a3b, b3l[1].v, acc, 0, 0, 0);
                float xm = xr[mb];
                msg[0] += xm * acc[0];
                msg[1] += xm * acc[1];
                msg[2] += xm * acc[2];
                msg[3] += xm * acc[3];
            }

            // ---- emit: msg store is UNCONDITIONAL (overflow edges just aren't in elist)
            *(float4*)(msgb + (size_t)e * 16 + q * 4) =
                make_float4(msg[0], msg[1], msg[2], msg[3]);

            int kk = __shfl(kv, lo16);      // broadcast bucket slot from the q==0 owner lane
            if (kk < CAP) {
                if (q == 0) elist[de * CAP + kv] = e;
            } else {
                float* xp = extra + (size_t)de * 16 + q * 4;
#pragma unroll
                for (int r = 0; r < 4; r++) atomicAdd(xp + r, msg[r]);
            }

            if (!hn) break;
            bt = btn; e = en; se = sen; de = den; kv = kvn;
        }
    }

    // ---------------- fused self path (blocks 945..1023) ----------------
    int sb = (int)blockIdx.x - 945;
    if (sb >= 0 && sb < 79) {
        int n = sb * 256 + t;
        bool act = (n < NN);
        float hv[16], yv[16];
        if (act) {
            const float4* h4 = (const float4*)(h_self + (size_t)n * 16);
#pragma unroll
            for (int k = 0; k < 4; k++) {
                float4 a = h4[k];
                hv[4*k+0] = a.x; hv[4*k+1] = a.y; hv[4*k+2] = a.z; hv[4*k+3] = a.w;
            }
        } else {
#pragma unroll
            for (int i = 0; i < 16; i++) hv[i] = 0.f;
        }
#pragma unroll
        for (int o = 0; o < 16; o++) {
            float a = 0.f;
#pragma unroll
            for (int i = 0; i < 16; i++) a += hv[i] * Wsf[i*16 + o];
            yv[o] = a;
        }
        if (act) {
            float4* y4 = (float4*)(y + (size_t)n * 16);
#pragma unroll
            for (int k = 0; k < 4; k++)
                y4[k] = make_float4(yv[4*k+0], yv[4*k+1], yv[4*k+2], yv[4*k+3]);
        }
        int lane = t & 63;
#pragma unroll
        for (int o = 0; o < 16; o++) {
            float a = act ? yv[o] : 0.f;
            float b = act ? yv[o]*yv[o] : 0.f;
#pragma unroll
            for (int off = 32; off > 0; off >>= 1) {
                a += __shfl_down(a, off);
                b += __shfl_down(b, off);
            }
            if (lane == 0) { red[wv][o] = a; red[wv][16 + o] = b; }
        }
        __syncthreads();
        if (t < 32) {
            float s = red[0][t] + red[1][t] + red[2][t] + red[3][t];
            atomicAdd(&bnacc[t], s);
        }
    }
}

// ---- finalize: per-node msg gather-sum + BN + tanh + add + relu + L2-normalize ----
// 4 threads per node; thread c owns components c*4..c*4+3. Per edge the node's 4
// adjacent lanes read a contiguous 64B msg row (coalesced).
__global__ __launch_bounds__(256) void final_kernel(
    const float* __restrict__ msgb, const int* __restrict__ elist,
    const int* __restrict__ cntp, const float* __restrict__ extra,
    const float* __restrict__ y, const float* __restrict__ bnacc,
    const float* __restrict__ gamma, const float* __restrict__ beta,
    float* __restrict__ out)
{
    int tb = blockIdx.x * 256 + threadIdx.x;
    int n = tb >> 2, c = tb & 3;
    if (n >= NN) return;

    int deg = cntp[n * CNTP];
    int m = deg < CAP ? deg : CAP;
    const float4* m4 = (const float4*)msgb;
    const int* el = elist + n * CAP;

    float ax = 0.f, ay = 0.f, az = 0.f, aw = 0.f;
    int k = 0;
    for (; k + 4 <= m; k += 4) {
        int e0 = el[k], e1 = el[k+1], e2 = el[k+2], e3 = el[k+3];
        float4 a0 = m4[(size_t)e0*4 + c];
        float4 a1 = m4[(size_t)e1*4 + c];
        float4 a2 = m4[(size_t)e2*4 + c];
        float4 a3 = m4[(size_t)e3*4 + c];
        ax += (a0.x + a1.x) + (a2.x + a3.x);
        ay += (a0.y + a1.y) + (a2.y + a3.y);
        az += (a0.z + a1.z) + (a2.z + a3.z);
        aw += (a0.w + a1.w) + (a2.w + a3.w);
    }
    for (; k < m; k++) {
        int e0 = el[k];
        float4 a0 = m4[(size_t)e0*4 + c];
        ax += a0.x; ay += a0.y; az += a0.z; aw += a0.w;
    }
    if (deg > CAP) {
        float4 a0 = *(const float4*)(extra + (size_t)n * 16 + c * 4);
        ax += a0.x; ay += a0.y; az += a0.z; aw += a0.w;
    }

    float4 yv4 = ((const float4*)y)[(size_t)n * 4 + c];
    float yv[4] = {yv4.x, yv4.y, yv4.z, yv4.w};
    float nb[4] = {ax, ay, az, aw};

    const float inv_n = 1.f / (float)NN;
    float z[4];
    float ss = 0.f;
#pragma unroll
    for (int r = 0; r < 4; r++) {
        int o = c * 4 + r;
        float mu  = bnacc[o] * inv_n;
        float var = bnacc[16 + o] * inv_n - mu * mu;
        float inv = rsqrtf(var + BN_EPS);
        float yy  = (yv[r] - mu) * inv * gamma[o] + beta[o];
        float tt  = tanhf(yy);
        float zz  = fmaxf(tt + nb[r], 0.f);
        z[r] = zz;
        ss += zz * zz;
    }
    // node-wide sum of squares across the 4 owning lanes (quad never crosses a wave)
    ss += __shfl_xor(ss, 1);
    ss += __shfl_xor(ss, 2);
    float nrm = sqrtf(ss);
    if (nrm == 0.f) nrm = 1.f;
    float rr = 1.f / nrm;
    *(float4*)(out + (size_t)n * 16 + c * 4) =
        make_float4(z[0]*rr, z[1]*rr, z[2]*rr, z[3]*rr);
}

extern "C" void kernel_launch(void* const* d_in, const int* in_sizes, int n_in,
                              void* d_out, int out_size, void* d_ws, size_t ws_size,
                              hipStream_t stream) {
    const float* h_neigh = (const float*)d_in[0];
    const float* h_self  = (const float*)d_in[1];
    const float* efeat   = (const float*)d_in[2];
    const int*   src     = (const int*)d_in[3];
    const int*   dst     = (const int*)d_in[4];
    const float* W_self  = (const float*)d_in[5];
    const float* gamma   = (const float*)d_in[6];
    const float* beta    = (const float*)d_in[7];
    const float* We1     = (const float*)d_in[8];
    const float* be1     = (const float*)d_in[9];
    const float* We2     = (const float*)d_in[10];
    const float* be2     = (const float*)d_in[11];
    float* out = (float*)d_out;

    char* ws = (char*)d_ws;
    float* msgb  = (float*)ws;
    int*   elist = (int*)(ws + ELIST_OFF);
    int*   cntp  = (int*)(ws + CNT_OFF);
    float* bnacc = (float*)(ws + BNACC_OFF);
    float* extra = (float*)(ws + EXTRA_OFF);
    float* y     = (float*)(ws + Y_OFF);

    // zero padded counters + BN accumulators + overflow buffer (ws poisoned 0xAA each call)
    hipMemsetAsync(ws + ZERO_OFF, 0, ZERO_BYTES, stream);

    // 1024 blocks = 4/CU resident; grid-stride over 5000 wave-tile groups;
    // blocks 945..1023 also do the self path.
    edge_kernel<<<1024, 256, 0, stream>>>(
        h_neigh, efeat, src, dst, We1, be1, We2, be2,
        msgb, elist, cntp, extra,
        h_self, W_self, y, bnacc);
    final_kernel<<<(NN * 4 + 255) / 256, 256, 0, stream>>>(
        msgb, elist, cntp, extra, y, bnacc, gamma, beta, out);
}